// Round 1
// baseline (513.009 us; speedup 1.0000x reference)
//
#include <hip/hip_runtime.h>

typedef __attribute__((ext_vector_type(8))) short short8;
typedef __attribute__((ext_vector_type(4))) float floatx4;

// ---------- bf16 helpers (manual, RNE) ----------
__device__ __forceinline__ unsigned short f2bf(float f) {
    unsigned u = __float_as_uint(f);
    u = u + 0x7fffu + ((u >> 16) & 1u);
    return (unsigned short)(u >> 16);
}
__device__ __forceinline__ float bf2f(short s) {
    return __uint_as_float(((unsigned)(unsigned short)s) << 16);
}

// ---------- async global->LDS, 16B per lane ----------
__device__ __forceinline__ void gl_lds16(const void* g, void* l) {
    __builtin_amdgcn_global_load_lds((const __attribute__((address_space(1))) void*)g,
                                     (__attribute__((address_space(3))) void*)l, 16, 0, 0);
}

// ---------- K0: convert x (fp32) -> bf16 ----------
__global__ __launch_bounds__(256) void convert_x_kernel(const float* __restrict__ x,
                                                        short* __restrict__ xb) {
    size_t i = ((size_t)blockIdx.x * 256 + threadIdx.x) * 8;
    float4 a = *(const float4*)(x + i);
    float4 b = *(const float4*)(x + i + 4);
    short8 r;
    r[0] = (short)f2bf(a.x); r[1] = (short)f2bf(a.y);
    r[2] = (short)f2bf(a.z); r[3] = (short)f2bf(a.w);
    r[4] = (short)f2bf(b.x); r[5] = (short)f2bf(b.y);
    r[6] = (short)f2bf(b.z); r[7] = (short)f2bf(b.w);
    *(short8*)(xb + i) = r;
}

// ---------- K1: transpose + convert fp32 (R x C) -> bf16 (C x R) ----------
__global__ __launch_bounds__(256) void transpose_conv_kernel(const float* __restrict__ in,
                                                             short* __restrict__ out,
                                                             int R, int C) {
    __shared__ float t[64][65];
    int c0 = blockIdx.x * 64, r0 = blockIdx.y * 64;
    int tid = threadIdx.x;
#pragma unroll
    for (int l = 0; l < 16; l++) {
        int idx = l * 256 + tid;
        int rr = idx >> 6, cc = idx & 63;
        t[rr][cc] = in[(size_t)(r0 + rr) * C + c0 + cc];
    }
    __syncthreads();
#pragma unroll
    for (int l = 0; l < 16; l++) {
        int idx = l * 256 + tid;
        int rr = idx >> 6, cc = idx & 63;
        out[(size_t)(c0 + rr) * R + r0 + cc] = (short)f2bf(t[cc][rr]);
    }
}

// ---------- K2: partial column sums of x over N (for x.mean(axis=1)) ----------
__global__ __launch_bounds__(256) void xmean_partial_kernel(const float* __restrict__ x,
                                                            float* __restrict__ part) {
    int bid = blockIdx.x;
    int b = bid >> 5, nch = bid & 31;   // 32 chunks of 64 rows
    int tid = threadIdx.x;
    float s0 = 0.f, s1 = 0.f, s2 = 0.f, s3 = 0.f;
    const float* xp = x + ((size_t)b * 2048 + nch * 64) * 1024;
    for (int n = 0; n < 64; n++) {
        const float* r = xp + (size_t)n * 1024;
        s0 += r[tid];
        s1 += r[tid + 256];
        s2 += r[tid + 512];
        s3 += r[tid + 768];
    }
    float* o = part + ((size_t)b * 32 + nch) * 1024;
    o[tid] = s0; o[tid + 256] = s1; o[tid + 512] = s2; o[tid + 768] = s3;
}

// ---------- K3: channel MLP:  ch = sigmoid(relu(m@W1+b1)@W2+b2) ----------
__global__ __launch_bounds__(256) void ch_kernel(const float* __restrict__ part,
                                                 const float* __restrict__ w1,
                                                 const float* __restrict__ b1,
                                                 const float* __restrict__ w2,
                                                 const float* __restrict__ b2,
                                                 float* __restrict__ ch) {
    int b = blockIdx.x, tid = threadIdx.x;
    __shared__ float mrow[1024];
    __shared__ float hid[256];
    for (int i = tid; i < 1024; i += 256) {
        float s = 0.f;
        for (int j = 0; j < 32; j++) s += part[((size_t)b * 32 + j) * 1024 + i];
        mrow[i] = s * (1.f / 2048.f);
    }
    __syncthreads();
    {
        float s = 0.f;
        for (int i = 0; i < 1024; i++) s += mrow[i] * w1[(size_t)i * 256 + tid];
        hid[tid] = fmaxf(s + b1[tid], 0.f);
    }
    __syncthreads();
    for (int c = tid; c < 1024; c += 256) {
        float s = 0.f;
        for (int j = 0; j < 256; j++) s += hid[j] * w2[(size_t)j * 1024 + c];
        ch[(size_t)b * 1024 + c] = 1.f / (1.f + expf(-(s + b2[0 + c - c] + b2[c] - b2[c] + b2[c])));
    }
}

// ---------- K4: qkv GEMM (bf16 MFMA 128x128x32), epilogue -> bf16 qkv, v scaled by ch ----------
__global__ __launch_bounds__(256) void gemm_qkv_kernel(const short* __restrict__ A,   // [16384][1024]
                                                       const short* __restrict__ BT,  // [3072][1024]
                                                       short* __restrict__ Cout,      // [16384][3072]
                                                       const float* __restrict__ ch)  // [8][1024]
{
    __shared__ __align__(16) short Ash[128 * 32];
    __shared__ __align__(16) short Bsh[128 * 32];
    const int tid = threadIdx.x;
    const int wave = tid >> 6, lane = tid & 63;
    const int bn = blockIdx.x, bm = blockIdx.y;
    const int wm = wave >> 1, wn = wave & 1;
    const int l4 = lane >> 2, kk = (lane & 3) * 8;
    const int lda = 1024, ldb = 1024;

    const short* Ag0 = A + (size_t)(bm * 128 + wave * 32 + l4) * lda + kk;
    const short* Ag1 = Ag0 + 16 * lda;
    const short* Bg0 = BT + (size_t)(bn * 128 + wave * 32 + l4) * ldb + kk;
    const short* Bg1 = Bg0 + 16 * ldb;
    short* lA0 = Ash + wave * 1024;
    short* lA1 = lA0 + 512;
    short* lB0 = Bsh + wave * 1024;
    short* lB1 = lB0 + 512;

    floatx4 acc[4][4];
    floatx4 zero = {0.f, 0.f, 0.f, 0.f};
#pragma unroll
    for (int i = 0; i < 4; i++)
#pragma unroll
        for (int j = 0; j < 4; j++) acc[i][j] = zero;

    const int ar = lane & 15, ak = (lane >> 4) * 8;

    for (int k0 = 0; k0 < 1024; k0 += 32) {
        gl_lds16(Ag0 + k0, lA0);
        gl_lds16(Ag1 + k0, lA1);
        gl_lds16(Bg0 + k0, lB0);
        gl_lds16(Bg1 + k0, lB1);
        __syncthreads();
        short8 af[4], bfr[4];
#pragma unroll
        for (int t = 0; t < 4; t++)
            af[t] = *(const short8*)(Ash + (wm * 64 + t * 16 + ar) * 32 + ak);
#pragma unroll
        for (int t = 0; t < 4; t++)
            bfr[t] = *(const short8*)(Bsh + (wn * 64 + t * 16 + ar) * 32 + ak);
#pragma unroll
        for (int i = 0; i < 4; i++)
#pragma unroll
            for (int j = 0; j < 4; j++)
                acc[i][j] = __builtin_amdgcn_mfma_f32_16x16x32_bf16(af[i], bfr[j], acc[i][j], 0, 0, 0);
        __syncthreads();
    }

    const int row0 = bm * 128 + wm * 64;
    const int col0 = bn * 128 + wn * 64;
#pragma unroll
    for (int i = 0; i < 4; i++) {
#pragma unroll
        for (int j = 0; j < 4; j++) {
            int col = col0 + j * 16 + (lane & 15);
#pragma unroll
            for (int r = 0; r < 4; r++) {
                int row = row0 + i * 16 + (lane >> 4) * 4 + r;
                float v = acc[i][j][r];
                if (col >= 2048) v *= ch[(size_t)((row >> 11) << 10) + (col - 2048)];
                Cout[(size_t)row * 3072 + col] = (short)f2bf(v);
            }
        }
    }
}

// ---------- K5: per-row q/k stats -> attn_base (SSIM formula) ----------
__global__ __launch_bounds__(256) void stats_kernel(const short* __restrict__ qkv,
                                                    const float* __restrict__ c1p,
                                                    const float* __restrict__ c2p,
                                                    float* __restrict__ attn) {
    int row = blockIdx.x * 4 + (threadIdx.x >> 6);
    int lane = threadIdx.x & 63;
    const short* q = qkv + (size_t)row * 3072;
    const short* k = q + 1024;
    float sq = 0.f, sk = 0.f, sqq = 0.f, skk = 0.f, sqk = 0.f;
#pragma unroll
    for (int j = 0; j < 2; j++) {
        int idx = j * 512 + lane * 8;
        short8 qv = *(const short8*)(q + idx);
        short8 kv = *(const short8*)(k + idx);
#pragma unroll
        for (int e = 0; e < 8; e++) {
            float qf = bf2f(qv[e]), kf = bf2f(kv[e]);
            sq += qf; sk += kf;
            sqq += qf * qf; skk += kf * kf; sqk += qf * kf;
        }
    }
#pragma unroll
    for (int m = 1; m < 64; m <<= 1) {
        sq += __shfl_xor(sq, m);
        sk += __shfl_xor(sk, m);
        sqq += __shfl_xor(sqq, m);
        skk += __shfl_xor(skk, m);
        sqk += __shfl_xor(sqk, m);
    }
    if (lane == 0) {
        const float C = 1024.f, invcm1 = 1.f / 1023.f;
        float c1 = *c1p, c2 = *c2p;
        float muq = sq / C, muk = sk / C;
        float sigqk = (sqk - C * muq * muk) * invcm1;
        float sigq2 = (sqq - C * muq * muq) * invcm1;
        float sigk2 = (skk - C * muk * muk) * invcm1;
        float num = (2.f * muq * muk + c1) * (2.f * sigqk + c2);
        float den = (muq * muq + muk * muk + c1) * (sigq2 + sigk2 + c2);
        float r = num / (den + 1e-7f);
        attn[row] = r * r;
    }
}

// ---------- block reduce helpers ----------
__device__ __forceinline__ float blk_sum(float v, float* buf) {
#pragma unroll
    for (int m = 1; m < 64; m <<= 1) v += __shfl_xor(v, m);
    int wave = threadIdx.x >> 6;
    if ((threadIdx.x & 63) == 0) buf[wave] = v;
    __syncthreads();
    float r = buf[0] + buf[1] + buf[2] + buf[3];
    __syncthreads();
    return r;
}
__device__ __forceinline__ float blk_max(float v, float* buf) {
#pragma unroll
    for (int m = 1; m < 64; m <<= 1) v = fmaxf(v, __shfl_xor(v, m));
    int wave = threadIdx.x >> 6;
    if ((threadIdx.x & 63) == 0) buf[wave] = v;
    __syncthreads();
    float r = fmaxf(fmaxf(buf[0], buf[1]), fmaxf(buf[2], buf[3]));
    __syncthreads();
    return r;
}

// ---------- K6: ODE step (conv1->GN->relu->conv2) + sigmoid + softmax ----------
__global__ __launch_bounds__(256) void ode_softmax_kernel(const float* __restrict__ attn,
                                                          const float* __restrict__ w1,   // (4,1,3)
                                                          const float* __restrict__ gng,  // (4)
                                                          const float* __restrict__ gnb,  // (4)
                                                          const float* __restrict__ w2,   // (1,4,3)
                                                          const float* __restrict__ b2,   // (1)
                                                          float* __restrict__ wgt) {
    int b = blockIdx.x, tid = threadIdx.x;
    __shared__ float A0[2048];
    __shared__ float H[4][2048];
    __shared__ float rbuf[4];
    for (int i = tid; i < 2048; i += 256) A0[i] = attn[(size_t)b * 2048 + i];
    __syncthreads();
    float w1l[12], w2l[12];
#pragma unroll
    for (int i = 0; i < 12; i++) { w1l[i] = w1[i]; w2l[i] = w2[i]; }
    float gg[4], gb[4];
#pragma unroll
    for (int c = 0; c < 4; c++) { gg[c] = gng[c]; gb[c] = gnb[c]; }

    float s0 = 0.f, ss0 = 0.f, s1 = 0.f, ss1 = 0.f;
    for (int i = tid; i < 2048; i += 256) {
        float le = (i > 0) ? A0[i - 1] : 0.f;
        float mi = A0[i];
        float ri = (i < 2047) ? A0[i + 1] : 0.f;
#pragma unroll
        for (int c = 0; c < 4; c++) {
            float h = w1l[c * 3] * le + w1l[c * 3 + 1] * mi + w1l[c * 3 + 2] * ri;
            H[c][i] = h;
            if (c < 2) { s0 += h; ss0 += h * h; } else { s1 += h; ss1 += h * h; }
        }
    }
    s0 = blk_sum(s0, rbuf);
    ss0 = blk_sum(ss0, rbuf);
    s1 = blk_sum(s1, rbuf);
    ss1 = blk_sum(ss1, rbuf);
    float mu0 = s0 / 4096.f, var0 = ss0 / 4096.f - mu0 * mu0;
    float mu1 = s1 / 4096.f, var1 = ss1 / 4096.f - mu1 * mu1;
    float is0 = 1.f / sqrtf(var0 + 1e-5f);
    float is1 = 1.f / sqrtf(var1 + 1e-5f);

    for (int i = tid; i < 2048; i += 256) {
#pragma unroll
        for (int c = 0; c < 4; c++) {
            float inv = (c < 2) ? is0 : is1;
            float mu = (c < 2) ? mu0 : mu1;
            float v = (H[c][i] - mu) * inv * gg[c] + gb[c];
            H[c][i] = fmaxf(v, 0.f);
        }
    }
    __syncthreads();

    float bias2 = b2[0];
    float myfa[8];
    float lmax = -1e30f;
#pragma unroll
    for (int ii = 0; ii < 8; ii++) {
        int i = tid + ii * 256;
        float y = bias2;
#pragma unroll
        for (int c = 0; c < 4; c++) {
            float le = (i > 0) ? H[c][i - 1] : 0.f;
            float mi = H[c][i];
            float ri = (i < 2047) ? H[c][i + 1] : 0.f;
            y += w2l[c * 3] * le + w2l[c * 3 + 1] * mi + w2l[c * 3 + 2] * ri;
        }
        float Av = A0[i] + y;             // A + dt*f(A), dt = 1
        float fa = 1.f / (1.f + expf(-Av));
        myfa[ii] = fa;
        lmax = fmaxf(lmax, fa);
    }
    float gmax = blk_max(lmax, rbuf);
    float lsum = 0.f;
#pragma unroll
    for (int ii = 0; ii < 8; ii++) {
        myfa[ii] = expf(myfa[ii] - gmax);
        lsum += myfa[ii];
    }
    float gsum = blk_sum(lsum, rbuf);
    float inv = 1.f / gsum;
#pragma unroll
    for (int ii = 0; ii < 8; ii++) wgt[(size_t)b * 2048 + tid + ii * 256] = myfa[ii] * inv;
}

// ---------- K7: out GEMM: out = w[row]*(v_scaled @ projT) + proj_b ----------
__global__ __launch_bounds__(256) void gemm_out_kernel(const short* __restrict__ qkv,   // v at +2048, ld 3072
                                                       const short* __restrict__ BT,    // projT [1024][1024]
                                                       const float* __restrict__ wgt,   // [16384]
                                                       const float* __restrict__ pb,    // [1024]
                                                       float* __restrict__ Out)         // [16384][1024]
{
    __shared__ __align__(16) short Ash[128 * 32];
    __shared__ __align__(16) short Bsh[128 * 32];
    const int tid = threadIdx.x;
    const int wave = tid >> 6, lane = tid & 63;
    const int bn = blockIdx.x, bm = blockIdx.y;
    const int wm = wave >> 1, wn = wave & 1;
    const int l4 = lane >> 2, kk = (lane & 3) * 8;
    const int lda = 3072, ldb = 1024;
    const short* A = qkv + 2048;

    const short* Ag0 = A + (size_t)(bm * 128 + wave * 32 + l4) * lda + kk;
    const short* Ag1 = Ag0 + 16 * lda;
    const short* Bg0 = BT + (size_t)(bn * 128 + wave * 32 + l4) * ldb + kk;
    const short* Bg1 = Bg0 + 16 * ldb;
    short* lA0 = Ash + wave * 1024;
    short* lA1 = lA0 + 512;
    short* lB0 = Bsh + wave * 1024;
    short* lB1 = lB0 + 512;

    floatx4 acc[4][4];
    floatx4 zero = {0.f, 0.f, 0.f, 0.f};
#pragma unroll
    for (int i = 0; i < 4; i++)
#pragma unroll
        for (int j = 0; j < 4; j++) acc[i][j] = zero;

    const int ar = lane & 15, ak = (lane >> 4) * 8;

    for (int k0 = 0; k0 < 1024; k0 += 32) {
        gl_lds16(Ag0 + k0, lA0);
        gl_lds16(Ag1 + k0, lA1);
        gl_lds16(Bg0 + k0, lB0);
        gl_lds16(Bg1 + k0, lB1);
        __syncthreads();
        short8 af[4], bfr[4];
#pragma unroll
        for (int t = 0; t < 4; t++)
            af[t] = *(const short8*)(Ash + (wm * 64 + t * 16 + ar) * 32 + ak);
#pragma unroll
        for (int t = 0; t < 4; t++)
            bfr[t] = *(const short8*)(Bsh + (wn * 64 + t * 16 + ar) * 32 + ak);
#pragma unroll
        for (int i = 0; i < 4; i++)
#pragma unroll
            for (int j = 0; j < 4; j++)
                acc[i][j] = __builtin_amdgcn_mfma_f32_16x16x32_bf16(af[i], bfr[j], acc[i][j], 0, 0, 0);
        __syncthreads();
    }

    const int row0 = bm * 128 + wm * 64;
    const int col0 = bn * 128 + wn * 64;
#pragma unroll
    for (int i = 0; i < 4; i++) {
#pragma unroll
        for (int j = 0; j < 4; j++) {
            int col = col0 + j * 16 + (lane & 15);
            float bias = pb[col];
#pragma unroll
            for (int r = 0; r < 4; r++) {
                int row = row0 + i * 16 + (lane >> 4) * 4 + r;
                Out[(size_t)row * 1024 + col] = wgt[row] * acc[i][j][r] + bias;
            }
        }
    }
}

extern "C" void kernel_launch(void* const* d_in, const int* in_sizes, int n_in,
                              void* d_out, int out_size, void* d_ws, size_t ws_size,
                              hipStream_t stream) {
    const float* x       = (const float*)d_in[0];
    const float* qkv_w   = (const float*)d_in[1];
    const float* c1      = (const float*)d_in[2];
    const float* c2      = (const float*)d_in[3];
    const float* conv1_w = (const float*)d_in[4];
    const float* gn_g    = (const float*)d_in[5];
    const float* gn_b    = (const float*)d_in[6];
    const float* conv2_w = (const float*)d_in[7];
    const float* conv2_b = (const float*)d_in[8];
    const float* ch_w1   = (const float*)d_in[9];
    const float* ch_b1   = (const float*)d_in[10];
    const float* ch_w2   = (const float*)d_in[11];
    const float* ch_b2   = (const float*)d_in[12];
    const float* proj_w  = (const float*)d_in[13];
    const float* proj_b  = (const float*)d_in[14];
    float* out = (float*)d_out;

    size_t off = 0;
    char* base = (char*)d_ws;
    auto carve = [&](size_t bytes) -> char* {
        char* p = base + off;
        off += (bytes + 255) & ~(size_t)255;
        return p;
    };
    short* x_bf  = (short*)carve((size_t)16777216 * 2);      // 33.6 MB
    short* qkvT  = (short*)carve((size_t)3072 * 1024 * 2);   // 6.3 MB
    short* projT = (short*)carve((size_t)1024 * 1024 * 2);   // 2.1 MB
    short* qkv   = (short*)carve((size_t)16384 * 3072 * 2);  // 100.7 MB
    float* attn  = (float*)carve((size_t)16384 * 4);
    float* wgt   = (float*)carve((size_t)16384 * 4);
    float* part  = (float*)carve((size_t)8 * 32 * 1024 * 4);
    float* chw   = (float*)carve((size_t)8 * 1024 * 4);

    convert_x_kernel<<<8192, 256, 0, stream>>>(x, x_bf);
    transpose_conv_kernel<<<dim3(48, 16), 256, 0, stream>>>(qkv_w, qkvT, 1024, 3072);
    transpose_conv_kernel<<<dim3(16, 16), 256, 0, stream>>>(proj_w, projT, 1024, 1024);
    xmean_partial_kernel<<<256, 256, 0, stream>>>(x, part);
    ch_kernel<<<8, 256, 0, stream>>>(part, ch_w1, ch_b1, ch_w2, ch_b2, chw);
    gemm_qkv_kernel<<<dim3(24, 128), 256, 0, stream>>>(x_bf, qkvT, qkv, chw);
    stats_kernel<<<4096, 256, 0, stream>>>(qkv, c1, c2, attn);
    ode_softmax_kernel<<<8, 256, 0, stream>>>(attn, conv1_w, gn_g, gn_b, conv2_w, conv2_b, wgt);
    gemm_out_kernel<<<dim3(8, 128), 256, 0, stream>>>(qkv, projT, wgt, proj_b, out);
}

// Round 2
// 456.194 us; speedup vs baseline: 1.1245x; 1.1245x over previous
//
#include <hip/hip_runtime.h>

typedef __attribute__((ext_vector_type(8))) short short8;
typedef __attribute__((ext_vector_type(4))) short short4v;
typedef __attribute__((ext_vector_type(4))) float floatx4;

// ---------- bf16 helpers (manual, RNE) ----------
__device__ __forceinline__ unsigned short f2bf(float f) {
    unsigned u = __float_as_uint(f);
    u = u + 0x7fffu + ((u >> 16) & 1u);
    return (unsigned short)(u >> 16);
}
__device__ __forceinline__ float bf2f(short s) {
    return __uint_as_float(((unsigned)(unsigned short)s) << 16);
}

// ---------- async global->LDS, 16B per lane ----------
__device__ __forceinline__ void gl_lds16(const void* g, void* l) {
    __builtin_amdgcn_global_load_lds((const __attribute__((address_space(1))) void*)g,
                                     (__attribute__((address_space(3))) void*)l, 16, 0, 0);
}

// ---------- K0: fused convert x->bf16 + partial column sums over N ----------
// 512 blocks: b = bid>>6 (batch), chunk = bid&63 (32 rows each)
__global__ __launch_bounds__(256) void convmean_kernel(const float* __restrict__ x,
                                                       short* __restrict__ xb,
                                                       float* __restrict__ part) {
    int bid = blockIdx.x;
    int b = bid >> 6, nch = bid & 63;
    int tid = threadIdx.x;
    size_t base = ((size_t)b * 2048 + nch * 32) * 1024;
    float s0 = 0.f, s1 = 0.f, s2 = 0.f, s3 = 0.f;
    int c0 = tid * 4;
    for (int r = 0; r < 32; r++) {
        const float* rp = x + base + (size_t)r * 1024 + c0;
        float4 v = *(const float4*)rp;
        s0 += v.x; s1 += v.y; s2 += v.z; s3 += v.w;
        short4v o;
        o[0] = (short)f2bf(v.x); o[1] = (short)f2bf(v.y);
        o[2] = (short)f2bf(v.z); o[3] = (short)f2bf(v.w);
        *(short4v*)(xb + base + (size_t)r * 1024 + c0) = o;
    }
    float* pp = part + ((size_t)b * 64 + nch) * 1024 + c0;
    float4 ps; ps.x = s0; ps.y = s1; ps.z = s2; ps.w = s3;
    *(float4*)pp = ps;
}

// ---------- K1: fused transpose+convert of qkv_w and proj_w ----------
__global__ __launch_bounds__(256) void transpose_conv_kernel(const float* __restrict__ w_qkv,
                                                             short* __restrict__ qkvT,
                                                             const float* __restrict__ w_proj,
                                                             short* __restrict__ projT) {
    __shared__ float t[64][65];
    int bx = blockIdx.x;
    const float* in; short* out; int C;
    int c0, r0 = blockIdx.y * 64;
    if (bx < 48) { in = w_qkv; out = qkvT; C = 3072; c0 = bx * 64; }
    else         { in = w_proj; out = projT; C = 1024; c0 = (bx - 48) * 64; }
    int tid = threadIdx.x;
#pragma unroll
    for (int l = 0; l < 16; l++) {
        int idx = l * 256 + tid;
        int rr = idx >> 6, cc = idx & 63;
        t[rr][cc] = in[(size_t)(r0 + rr) * C + c0 + cc];
    }
    __syncthreads();
#pragma unroll
    for (int l = 0; l < 16; l++) {
        int idx = l * 256 + tid;
        int rr = idx >> 6, cc = idx & 63;
        out[(size_t)(c0 + rr) * 1024 + r0 + cc] = (short)f2bf(t[cc][rr]);
    }
}

// ---------- K2: channel MLP:  ch = sigmoid(relu(m@W1+b1)@W2+b2) ----------
__global__ __launch_bounds__(256) void ch_kernel(const float* __restrict__ part,
                                                 const float* __restrict__ w1,
                                                 const float* __restrict__ b1,
                                                 const float* __restrict__ w2,
                                                 const float* __restrict__ b2,
                                                 float* __restrict__ ch) {
    int b = blockIdx.x, tid = threadIdx.x;
    __shared__ float mrow[1024];
    __shared__ float hid[256];
    for (int i = tid; i < 1024; i += 256) {
        float s = 0.f;
        for (int j = 0; j < 64; j++) s += part[((size_t)b * 64 + j) * 1024 + i];
        mrow[i] = s * (1.f / 2048.f);
    }
    __syncthreads();
    {
        float s = 0.f;
        for (int i = 0; i < 1024; i++) s += mrow[i] * w1[(size_t)i * 256 + tid];
        hid[tid] = fmaxf(s + b1[tid], 0.f);
    }
    __syncthreads();
    for (int c = tid; c < 1024; c += 256) {
        float s = 0.f;
        for (int j = 0; j < 256; j++) s += hid[j] * w2[(size_t)j * 1024 + c];
        ch[(size_t)b * 1024 + c] = 1.f / (1.f + expf(-(s + b2[c])));
    }
}

// ---------- K3: qkv GEMM, 128x128 tile, BK=64 (two K=32 stages per barrier) ----------
// XCD-aware swizzle: bm = (j%16)*8 + (id&7), bn = j/16
__global__ __launch_bounds__(256) void gemm_qkv_kernel(const short* __restrict__ A,   // [16384][1024]
                                                       const short* __restrict__ BT,  // [3072][1024]
                                                       short* __restrict__ Cout,      // [16384][3072]
                                                       const float* __restrict__ ch)  // [8][1024]
{
    __shared__ __align__(16) short Ash[2 * 128 * 32];
    __shared__ __align__(16) short Bsh[2 * 128 * 32];
    const int tid = threadIdx.x;
    const int wave = tid >> 6, lane = tid & 63;
    const int id = blockIdx.x;
    const int xcd = id & 7, j = id >> 3;
    const int bm = (j & 15) * 8 + xcd;
    const int bn = j >> 4;
    const int wm = wave >> 1, wn = wave & 1;
    const int l4 = lane >> 2, kk = (lane & 3) * 8;
    const int lda = 1024, ldb = 1024;

    const short* Ag = A + (size_t)(bm * 128 + wave * 32 + l4) * lda + kk;
    const short* Bg = BT + (size_t)(bn * 128 + wave * 32 + l4) * ldb + kk;
    short* lA = Ash + wave * 1024;
    short* lB = Bsh + wave * 1024;

    floatx4 acc[4][4];
    floatx4 zero = {0.f, 0.f, 0.f, 0.f};
#pragma unroll
    for (int i = 0; i < 4; i++)
#pragma unroll
        for (int jj = 0; jj < 4; jj++) acc[i][jj] = zero;

    const int ar = lane & 15, ak = (lane >> 4) * 8;

    for (int k0 = 0; k0 < 1024; k0 += 64) {
#pragma unroll
        for (int h = 0; h < 2; h++) {
            gl_lds16(Ag + k0 + h * 32, lA + h * 4096);
            gl_lds16(Ag + 16 * lda + k0 + h * 32, lA + h * 4096 + 512);
            gl_lds16(Bg + k0 + h * 32, lB + h * 4096);
            gl_lds16(Bg + 16 * ldb + k0 + h * 32, lB + h * 4096 + 512);
        }
        __syncthreads();
#pragma unroll
        for (int h = 0; h < 2; h++) {
            short8 af[4], bfr[4];
#pragma unroll
            for (int t = 0; t < 4; t++)
                af[t] = *(const short8*)(Ash + h * 4096 + (wm * 64 + t * 16 + ar) * 32 + ak);
#pragma unroll
            for (int t = 0; t < 4; t++)
                bfr[t] = *(const short8*)(Bsh + h * 4096 + (wn * 64 + t * 16 + ar) * 32 + ak);
#pragma unroll
            for (int i = 0; i < 4; i++)
#pragma unroll
                for (int jj = 0; jj < 4; jj++)
                    acc[i][jj] = __builtin_amdgcn_mfma_f32_16x16x32_bf16(af[i], bfr[jj], acc[i][jj], 0, 0, 0);
        }
        __syncthreads();
    }

    const int row0 = bm * 128 + wm * 64;
    const int col0 = bn * 128 + wn * 64;
#pragma unroll
    for (int i = 0; i < 4; i++) {
#pragma unroll
        for (int jj = 0; jj < 4; jj++) {
            int col = col0 + jj * 16 + (lane & 15);
#pragma unroll
            for (int r = 0; r < 4; r++) {
                int row = row0 + i * 16 + (lane >> 4) * 4 + r;
                float v = acc[i][jj][r];
                if (col >= 2048) v *= ch[(size_t)((row >> 11) << 10) + (col - 2048)];
                Cout[(size_t)row * 3072 + col] = (short)f2bf(v);
            }
        }
    }
}

// ---------- K4: per-row q/k stats -> attn_base (SSIM formula) ----------
__global__ __launch_bounds__(256) void stats_kernel(const short* __restrict__ qkv,
                                                    const float* __restrict__ c1p,
                                                    const float* __restrict__ c2p,
                                                    float* __restrict__ attn) {
    int row = blockIdx.x * 4 + (threadIdx.x >> 6);
    int lane = threadIdx.x & 63;
    const short* q = qkv + (size_t)row * 3072;
    const short* k = q + 1024;
    float sq = 0.f, sk = 0.f, sqq = 0.f, skk = 0.f, sqk = 0.f;
#pragma unroll
    for (int j = 0; j < 2; j++) {
        int idx = j * 512 + lane * 8;
        short8 qv = *(const short8*)(q + idx);
        short8 kv = *(const short8*)(k + idx);
#pragma unroll
        for (int e = 0; e < 8; e++) {
            float qf = bf2f(qv[e]), kf = bf2f(kv[e]);
            sq += qf; sk += kf;
            sqq += qf * qf; skk += kf * kf; sqk += qf * kf;
        }
    }
#pragma unroll
    for (int m = 1; m < 64; m <<= 1) {
        sq += __shfl_xor(sq, m);
        sk += __shfl_xor(sk, m);
        sqq += __shfl_xor(sqq, m);
        skk += __shfl_xor(skk, m);
        sqk += __shfl_xor(sqk, m);
    }
    if (lane == 0) {
        const float C = 1024.f, invcm1 = 1.f / 1023.f;
        float c1 = *c1p, c2 = *c2p;
        float muq = sq / C, muk = sk / C;
        float sigqk = (sqk - C * muq * muk) * invcm1;
        float sigq2 = (sqq - C * muq * muq) * invcm1;
        float sigk2 = (skk - C * muk * muk) * invcm1;
        float num = (2.f * muq * muk + c1) * (2.f * sigqk + c2);
        float den = (muq * muq + muk * muk + c1) * (sigq2 + sigk2 + c2);
        float r = num / (den + 1e-7f);
        attn[row] = r * r;
    }
}

// ---------- block reduce helpers ----------
__device__ __forceinline__ float blk_sum(float v, float* buf) {
#pragma unroll
    for (int m = 1; m < 64; m <<= 1) v += __shfl_xor(v, m);
    int wave = threadIdx.x >> 6;
    if ((threadIdx.x & 63) == 0) buf[wave] = v;
    __syncthreads();
    float r = buf[0] + buf[1] + buf[2] + buf[3];
    __syncthreads();
    return r;
}
__device__ __forceinline__ float blk_max(float v, float* buf) {
#pragma unroll
    for (int m = 1; m < 64; m <<= 1) v = fmaxf(v, __shfl_xor(v, m));
    int wave = threadIdx.x >> 6;
    if ((threadIdx.x & 63) == 0) buf[wave] = v;
    __syncthreads();
    float r = fmaxf(fmaxf(buf[0], buf[1]), fmaxf(buf[2], buf[3]));
    __syncthreads();
    return r;
}

// ---------- K5: ODE step (conv1->GN->relu->conv2) + sigmoid + softmax ----------
__global__ __launch_bounds__(256) void ode_softmax_kernel(const float* __restrict__ attn,
                                                          const float* __restrict__ w1,   // (4,1,3)
                                                          const float* __restrict__ gng,  // (4)
                                                          const float* __restrict__ gnb,  // (4)
                                                          const float* __restrict__ w2,   // (1,4,3)
                                                          const float* __restrict__ b2,   // (1)
                                                          float* __restrict__ wgt) {
    int b = blockIdx.x, tid = threadIdx.x;
    __shared__ float A0[2048];
    __shared__ float H[4][2048];
    __shared__ float rbuf[4];
    for (int i = tid; i < 2048; i += 256) A0[i] = attn[(size_t)b * 2048 + i];
    __syncthreads();
    float w1l[12], w2l[12];
#pragma unroll
    for (int i = 0; i < 12; i++) { w1l[i] = w1[i]; w2l[i] = w2[i]; }
    float gg[4], gb[4];
#pragma unroll
    for (int c = 0; c < 4; c++) { gg[c] = gng[c]; gb[c] = gnb[c]; }

    float s0 = 0.f, ss0 = 0.f, s1 = 0.f, ss1 = 0.f;
    for (int i = tid; i < 2048; i += 256) {
        float le = (i > 0) ? A0[i - 1] : 0.f;
        float mi = A0[i];
        float ri = (i < 2047) ? A0[i + 1] : 0.f;
#pragma unroll
        for (int c = 0; c < 4; c++) {
            float h = w1l[c * 3] * le + w1l[c * 3 + 1] * mi + w1l[c * 3 + 2] * ri;
            H[c][i] = h;
            if (c < 2) { s0 += h; ss0 += h * h; } else { s1 += h; ss1 += h * h; }
        }
    }
    s0 = blk_sum(s0, rbuf);
    ss0 = blk_sum(ss0, rbuf);
    s1 = blk_sum(s1, rbuf);
    ss1 = blk_sum(ss1, rbuf);
    float mu0 = s0 / 4096.f, var0 = ss0 / 4096.f - mu0 * mu0;
    float mu1 = s1 / 4096.f, var1 = ss1 / 4096.f - mu1 * mu1;
    float is0 = 1.f / sqrtf(var0 + 1e-5f);
    float is1 = 1.f / sqrtf(var1 + 1e-5f);

    for (int i = tid; i < 2048; i += 256) {
#pragma unroll
        for (int c = 0; c < 4; c++) {
            float inv = (c < 2) ? is0 : is1;
            float mu = (c < 2) ? mu0 : mu1;
            float v = (H[c][i] - mu) * inv * gg[c] + gb[c];
            H[c][i] = fmaxf(v, 0.f);
        }
    }
    __syncthreads();

    float bias2 = b2[0];
    float myfa[8];
    float lmax = -1e30f;
#pragma unroll
    for (int ii = 0; ii < 8; ii++) {
        int i = tid + ii * 256;
        float y = bias2;
#pragma unroll
        for (int c = 0; c < 4; c++) {
            float le = (i > 0) ? H[c][i - 1] : 0.f;
            float mi = H[c][i];
            float ri = (i < 2047) ? H[c][i + 1] : 0.f;
            y += w2l[c * 3] * le + w2l[c * 3 + 1] * mi + w2l[c * 3 + 2] * ri;
        }
        float Av = A0[i] + y;             // A + dt*f(A), dt = 1
        float fa = 1.f / (1.f + expf(-Av));
        myfa[ii] = fa;
        lmax = fmaxf(lmax, fa);
    }
    float gmax = blk_max(lmax, rbuf);
    float lsum = 0.f;
#pragma unroll
    for (int ii = 0; ii < 8; ii++) {
        myfa[ii] = expf(myfa[ii] - gmax);
        lsum += myfa[ii];
    }
    float gsum = blk_sum(lsum, rbuf);
    float inv = 1.f / gsum;
#pragma unroll
    for (int ii = 0; ii < 8; ii++) wgt[(size_t)b * 2048 + tid + ii * 256] = myfa[ii] * inv;
}

// ---------- K6: out GEMM, BK=64: out = w[row]*(v_scaled @ projT) + proj_b ----------
__global__ __launch_bounds__(256) void gemm_out_kernel(const short* __restrict__ qkv,   // v at +2048, ld 3072
                                                       const short* __restrict__ BT,    // projT [1024][1024]
                                                       const float* __restrict__ wgt,   // [16384]
                                                       const float* __restrict__ pb,    // [1024]
                                                       float* __restrict__ Out)         // [16384][1024]
{
    __shared__ __align__(16) short Ash[2 * 128 * 32];
    __shared__ __align__(16) short Bsh[2 * 128 * 32];
    const int tid = threadIdx.x;
    const int wave = tid >> 6, lane = tid & 63;
    const int id = blockIdx.x;
    const int xcd = id & 7, j = id >> 3;
    const int bm = (j & 15) * 8 + xcd;
    const int bn = j >> 4;
    const int wm = wave >> 1, wn = wave & 1;
    const int l4 = lane >> 2, kk = (lane & 3) * 8;
    const int lda = 3072, ldb = 1024;
    const short* A = qkv + 2048;

    const short* Ag = A + (size_t)(bm * 128 + wave * 32 + l4) * lda + kk;
    const short* Bg = BT + (size_t)(bn * 128 + wave * 32 + l4) * ldb + kk;
    short* lA = Ash + wave * 1024;
    short* lB = Bsh + wave * 1024;

    floatx4 acc[4][4];
    floatx4 zero = {0.f, 0.f, 0.f, 0.f};
#pragma unroll
    for (int i = 0; i < 4; i++)
#pragma unroll
        for (int jj = 0; jj < 4; jj++) acc[i][jj] = zero;

    const int ar = lane & 15, ak = (lane >> 4) * 8;

    for (int k0 = 0; k0 < 1024; k0 += 64) {
#pragma unroll
        for (int h = 0; h < 2; h++) {
            gl_lds16(Ag + k0 + h * 32, lA + h * 4096);
            gl_lds16(Ag + 16 * lda + k0 + h * 32, lA + h * 4096 + 512);
            gl_lds16(Bg + k0 + h * 32, lB + h * 4096);
            gl_lds16(Bg + 16 * ldb + k0 + h * 32, lB + h * 4096 + 512);
        }
        __syncthreads();
#pragma unroll
        for (int h = 0; h < 2; h++) {
            short8 af[4], bfr[4];
#pragma unroll
            for (int t = 0; t < 4; t++)
                af[t] = *(const short8*)(Ash + h * 4096 + (wm * 64 + t * 16 + ar) * 32 + ak);
#pragma unroll
            for (int t = 0; t < 4; t++)
                bfr[t] = *(const short8*)(Bsh + h * 4096 + (wn * 64 + t * 16 + ar) * 32 + ak);
#pragma unroll
            for (int i = 0; i < 4; i++)
#pragma unroll
                for (int jj = 0; jj < 4; jj++)
                    acc[i][jj] = __builtin_amdgcn_mfma_f32_16x16x32_bf16(af[i], bfr[jj], acc[i][jj], 0, 0, 0);
        }
        __syncthreads();
    }

    const int row0 = bm * 128 + wm * 64;
    const int col0 = bn * 128 + wn * 64;
#pragma unroll
    for (int i = 0; i < 4; i++) {
#pragma unroll
        for (int jj = 0; jj < 4; jj++) {
            int col = col0 + jj * 16 + (lane & 15);
            float bias = pb[col];
#pragma unroll
            for (int r = 0; r < 4; r++) {
                int row = row0 + i * 16 + (lane >> 4) * 4 + r;
                Out[(size_t)row * 1024 + col] = wgt[row] * acc[i][jj][r] + bias;
            }
        }
    }
}

extern "C" void kernel_launch(void* const* d_in, const int* in_sizes, int n_in,
                              void* d_out, int out_size, void* d_ws, size_t ws_size,
                              hipStream_t stream) {
    const float* x       = (const float*)d_in[0];
    const float* qkv_w   = (const float*)d_in[1];
    const float* c1      = (const float*)d_in[2];
    const float* c2      = (const float*)d_in[3];
    const float* conv1_w = (const float*)d_in[4];
    const float* gn_g    = (const float*)d_in[5];
    const float* gn_b    = (const float*)d_in[6];
    const float* conv2_w = (const float*)d_in[7];
    const float* conv2_b = (const float*)d_in[8];
    const float* ch_w1   = (const float*)d_in[9];
    const float* ch_b1   = (const float*)d_in[10];
    const float* ch_w2   = (const float*)d_in[11];
    const float* ch_b2   = (const float*)d_in[12];
    const float* proj_w  = (const float*)d_in[13];
    const float* proj_b  = (const float*)d_in[14];
    float* out = (float*)d_out;

    size_t off = 0;
    char* base = (char*)d_ws;
    auto carve = [&](size_t bytes) -> char* {
        char* p = base + off;
        off += (bytes + 255) & ~(size_t)255;
        return p;
    };
    short* x_bf  = (short*)carve((size_t)16777216 * 2);      // 33.6 MB
    short* qkvT  = (short*)carve((size_t)3072 * 1024 * 2);   // 6.3 MB
    short* projT = (short*)carve((size_t)1024 * 1024 * 2);   // 2.1 MB
    short* qkv   = (short*)carve((size_t)16384 * 3072 * 2);  // 100.7 MB
    float* attn  = (float*)carve((size_t)16384 * 4);
    float* wgt   = (float*)carve((size_t)16384 * 4);
    float* part  = (float*)carve((size_t)8 * 64 * 1024 * 4);
    float* chw   = (float*)carve((size_t)8 * 1024 * 4);

    convmean_kernel<<<512, 256, 0, stream>>>(x, x_bf, part);
    transpose_conv_kernel<<<dim3(64, 16), 256, 0, stream>>>(qkv_w, qkvT, proj_w, projT);
    ch_kernel<<<8, 256, 0, stream>>>(part, ch_w1, ch_b1, ch_w2, ch_b2, chw);
    gemm_qkv_kernel<<<3072, 256, 0, stream>>>(x_bf, qkvT, qkv, chw);
    stats_kernel<<<4096, 256, 0, stream>>>(qkv, c1, c2, attn);
    ode_softmax_kernel<<<8, 256, 0, stream>>>(attn, conv1_w, gn_g, gn_b, conv2_w, conv2_b, wgt);
    gemm_out_kernel<<<1024, 256, 0, stream>>>(qkv, projT, wgt, proj_b, out);
}